// Round 5
// baseline (393.666 us; speedup 1.0000x reference)
//
#include <hip/hip_runtime.h>

#define H 32
#define GPB 16  // 32-lane groups per 512-thread block

// tanh(x) = 1 - 2/(1 + exp2(x * 2*log2(e))); saturates correctly at +/-inf.
__device__ __forceinline__ float fast_tanh(float x) {
    float e = __builtin_amdgcn_exp2f(x * 2.8853900817779268f);
    float r = __builtin_amdgcn_rcpf(e + 1.0f);
    return fmaf(-2.0f, r, 1.0f);
}

// acc += (quad-lane q's copy of p) * w — one v_fmac_f32_dpp.
// p regs are only written by ds_bpermute (lgkmcnt-guarded) => no VALU->DPP hazard.
#define QFMA(acc, p, w, q) \
    asm("v_fmac_f32_dpp %0, %1, %2 quad_perm:[" #q "," #q "," #q "," #q "] row_mask:0xf bank_mask:0xf" \
        : "+v"(acc) : "v"(p), "v"(w))

// Column i of the mat-vec: round-robin over the 4 accumulators (8-cycle reuse
// distance >= FMA latency). Per-accumulator order identical to baseline.
#define MV4(i) \
    QFMA(a0, p[i], whh[i],      0); \
    QFMA(a1, p[i], whh[8 + i],  1); \
    QFMA(a2, p[i], whh[16 + i], 2); \
    QFMA(a3, p[i], whh[24 + i], 3)

// dpp mov, bound_ctrl=1: shifted-in lanes contribute 0.
#define DPPMOV(x, ctrl) \
    __int_as_float(__builtin_amdgcn_update_dpp(0, __float_as_int(x), (ctrl), 0xf, 0xf, true))
#define ROW_SHR1 0x111
#define ROW_SHR2 0x112
#define ROW_SHR4 0x114

// x-projection: 5 FMAs off broadcast-loaded onehot/reward.
#define XP(oh, rwc) fmaf((oh).x, wih0, fmaf((oh).y, wih1, fmaf((oh).z, wih2, \
                     fmaf((oh).w, wih3, fmaf((rwc), wih4, bias)))))

// 512-thread blocks, 1 block/CU -> 8 waves/CU = 2 waves per SIMD. A single
// wave issues VALU at ~1/4cyc (measured: VALUBusy caps ~50% at 1 wave/SIMD);
// two co-resident waves interleave to fill the 2-cyc execute slots.
__global__ __launch_bounds__(512, 2) void rnn_fused(
    const float* __restrict__ onehot,   // [B,T,4]
    const float* __restrict__ rewards,  // [B,T]
    const float* __restrict__ W_ih,     // [H,5]
    const float* __restrict__ W_hh,     // [H,H]
    const float* __restrict__ b_ih,     // [H]
    const float* __restrict__ b_hh,     // [H]
    const float* __restrict__ W_ro,     // [4,H]
    const float* __restrict__ b_ro,     // [4]
    float* __restrict__ out_logits,     // [B,T,4]
    float* __restrict__ out_hT,         // [B,H]
    int T)
{
    const int tid = threadIdx.x;
    const int u   = tid & 31;            // hidden unit owned by this lane
    const int wl  = tid & 63;            // lane within the wave64
    const int b   = blockIdx.x * GPB + (tid >> 5);
    const int qp  = u & 3;               // quad position -> which 8-chunk we gather
    const int r   = u >> 3;              // readout row this lane contributes to
    const bool hi = ((u >> 2) & 1) != 0; // which half of our chunk for readout
    const bool writer = (u & 7) == 7;    // lane that stores logit row r

    // bpermute byte-indices for our 8-chunk: lane (groupbase + 8*qp + i)
    const int ib = ((wl & 32) + 8 * qp) << 2;
    const int idx0 = ib +  0, idx1 = ib +  4, idx2 = ib +  8, idx3 = ib + 12;
    const int idx4 = ib + 16, idx5 = ib + 20, idx6 = ib + 24, idx7 = ib + 28;

    // ---- persistent per-lane weights ----
    float whh[H];
#pragma unroll
    for (int k = 0; k < 8; ++k) {
        float4 w = *(const float4*)(W_hh + u * H + 4 * k);
        whh[4*k+0] = w.x; whh[4*k+1] = w.y; whh[4*k+2] = w.z; whh[4*k+3] = w.w;
    }
    const float wih0 = W_ih[u*5+0], wih1 = W_ih[u*5+1], wih2 = W_ih[u*5+2],
                wih3 = W_ih[u*5+3], wih4 = W_ih[u*5+4];
    const float bias = b_ih[u] + b_hh[u];
    const float4 wr4 = *(const float4*)(W_ro + r * H + qp * 8 + (hi ? 4 : 0));
    const float bro = b_ro[r];

    const float* oh_ptr = onehot  + (size_t)b * T * 4;
    const float* rw_ptr = rewards + (size_t)b * T;
    float*       lg_ptr = out_logits + (size_t)b * T * 4;

    // ---- two input-register banks (X: oh0..3/rwv, Y: qh0..3/qrw) so the
    //      x-projection can be computed INSIDE each step (gather-latency
    //      filler) without being clobbered by the next prefetch ----
    float4 oh0, oh1, oh2, oh3, rwv;
    float4 qh0, qh1, qh2, qh3, qrw;

    auto loadX = [&](int t) {
        oh0 = *(const float4*)(oh_ptr + (size_t)t * 4);
        oh1 = *(const float4*)(oh_ptr + (size_t)(t + 1) * 4);
        oh2 = *(const float4*)(oh_ptr + (size_t)(t + 2) * 4);
        oh3 = *(const float4*)(oh_ptr + (size_t)(t + 3) * 4);
        rwv = *(const float4*)(rw_ptr + t);
    };
    auto loadY = [&](int t) {
        qh0 = *(const float4*)(oh_ptr + (size_t)t * 4);
        qh1 = *(const float4*)(oh_ptr + (size_t)(t + 1) * 4);
        qh2 = *(const float4*)(oh_ptr + (size_t)(t + 2) * 4);
        qh3 = *(const float4*)(oh_ptr + (size_t)(t + 3) * 4);
        qrw = *(const float4*)(rw_ptr + t);
    };

    float hj = 0.0f;                     // h^{(-1)} = 0
    float pA[8], pB[8];                  // double-buffered gathered chunk

    // logits_t from a gathered h^{(t)} chunk buffer
    auto readout = [&](const float (&p)[8], int t) {
        float s0 = hi ? p[4] : p[0];
        float s1 = hi ? p[5] : p[1];
        float s2 = hi ? p[6] : p[2];
        float s3 = hi ? p[7] : p[3];
        float s = fmaf(s3, wr4.w, fmaf(s2, wr4.z, fmaf(s1, wr4.y, s0 * wr4.x)));
        s += DPPMOV(s, ROW_SHR1);
        s += DPPMOV(s, ROW_SHR2);
        s += DPPMOV(s, ROW_SHR4);        // lane (8r+7) holds full dot of row r
        if (writer) lg_ptr[(size_t)t * 4 + r] = s + bro;
    };

    // One recurrence step. Gather of h^{(t-1)} is issued first; readout of
    // h^{(t-2)} plus the x-projection fill the bpermute latency; then the
    // round-robin mat-vec and tanh.
    auto step = [&](float (&pN)[8], const float (&pO)[8],
                    const float4& oh, float rwc, int t, bool ro) {
        const int hb = __float_as_int(hj);
        pN[0] = __int_as_float(__builtin_amdgcn_ds_bpermute(idx0, hb));
        pN[1] = __int_as_float(__builtin_amdgcn_ds_bpermute(idx1, hb));
        pN[2] = __int_as_float(__builtin_amdgcn_ds_bpermute(idx2, hb));
        pN[3] = __int_as_float(__builtin_amdgcn_ds_bpermute(idx3, hb));
        pN[4] = __int_as_float(__builtin_amdgcn_ds_bpermute(idx4, hb));
        pN[5] = __int_as_float(__builtin_amdgcn_ds_bpermute(idx5, hb));
        pN[6] = __int_as_float(__builtin_amdgcn_ds_bpermute(idx6, hb));
        pN[7] = __int_as_float(__builtin_amdgcn_ds_bpermute(idx7, hb));
        if (ro) readout(pO, t - 2);      // latency filler (depends only on pO)
        const float xp = XP(oh, rwc);    // more filler (prefetched regs only)
        float (&p)[8] = pN;
        float a0 = xp, a1 = 0.f, a2 = 0.f, a3 = 0.f;
        MV4(0); MV4(1); MV4(2); MV4(3); MV4(4); MV4(5); MV4(6); MV4(7);
        hj = fast_tanh((a0 + a1) + (a2 + a3));
    };

    // ---- prologue: banks X=(t 0..3), Y=(t 4..7); steps 0..7 peeled ----
    loadX(0);
    loadY(4);
    step(pA, pB, oh0, rwv.x, 0, false);
    step(pB, pA, oh1, rwv.y, 1, false);
    step(pA, pB, oh2, rwv.z, 2, true);
    step(pB, pA, oh3, rwv.w, 3, true);
    loadX(8);                            // refill X for t = 8..11
    step(pA, pB, qh0, qrw.x, 4, true);
    step(pB, pA, qh1, qrw.y, 5, true);
    step(pA, pB, qh2, qrw.z, 6, true);
    step(pB, pA, qh3, qrw.w, 7, true);

    // ---- steady state: 8 steps per iteration, banks ping-pong ----
    for (int tb = 8; tb < T; tb += 8) {
        if (tb + 4 < T) loadY(tb + 4);   // refill Y while X block runs
        step(pA, pB, oh0, rwv.x, tb + 0, true);
        step(pB, pA, oh1, rwv.y, tb + 1, true);
        step(pA, pB, oh2, rwv.z, tb + 2, true);
        step(pB, pA, oh3, rwv.w, tb + 3, true);
        if (tb + 8 < T) loadX(tb + 8);   // refill X while Y block runs
        step(pA, pB, qh0, qrw.x, tb + 4, true);
        step(pB, pA, qh1, qrw.y, tb + 5, true);
        step(pA, pB, qh2, qrw.z, tb + 6, true);
        step(pB, pA, qh3, qrw.w, tb + 7, true);
    }

    // ---- epilogue (last step was t = T-1, wrote pB = gather(h^{T-2})) ----
    readout(pB, T - 2);
    {
        const int hb = __float_as_int(hj);   // hj = h^{(T-1)}
        pA[0] = __int_as_float(__builtin_amdgcn_ds_bpermute(idx0, hb));
        pA[1] = __int_as_float(__builtin_amdgcn_ds_bpermute(idx1, hb));
        pA[2] = __int_as_float(__builtin_amdgcn_ds_bpermute(idx2, hb));
        pA[3] = __int_as_float(__builtin_amdgcn_ds_bpermute(idx3, hb));
        pA[4] = __int_as_float(__builtin_amdgcn_ds_bpermute(idx4, hb));
        pA[5] = __int_as_float(__builtin_amdgcn_ds_bpermute(idx5, hb));
        pA[6] = __int_as_float(__builtin_amdgcn_ds_bpermute(idx6, hb));
        pA[7] = __int_as_float(__builtin_amdgcn_ds_bpermute(idx7, hb));
    }
    readout(pA, T - 1);                  // logits_{T-1} from h^{(T-1)}
    out_hT[(size_t)b * H + u] = hj;      // h_T
}

extern "C" void kernel_launch(void* const* d_in, const int* in_sizes, int n_in,
                              void* d_out, int out_size, void* d_ws, size_t ws_size,
                              hipStream_t stream) {
    const float* onehot  = (const float*)d_in[0];
    const float* rewards = (const float*)d_in[1];
    const float* W_ih    = (const float*)d_in[2];
    const float* W_hh    = (const float*)d_in[3];
    const float* b_ih    = (const float*)d_in[4];
    const float* b_hh    = (const float*)d_in[5];
    const float* W_ro    = (const float*)d_in[6];
    const float* b_ro    = (const float*)d_in[7];

    const int T = 1024;                  // per setup_inputs()
    const int B = in_sizes[1] / T;       // in_sizes[1] = B*T

    float* out_logits = (float*)d_out;                        // [B,T,4]
    float* out_hT     = (float*)d_out + (size_t)B * T * 4;    // [B,H]

    dim3 block(512);                     // 8 waves/block, 1 block/CU -> 2 waves/SIMD
    dim3 grid(B / GPB);                  // = 128 blocks (half the CUs, doubly occupied)
    rnn_fused<<<grid, block, 0, stream>>>(onehot, rewards, W_ih, W_hh,
                                          b_ih, b_hh, W_ro, b_ro,
                                          out_logits, out_hT, T);
}

// Round 6
// 367.969 us; speedup vs baseline: 1.0698x; 1.0698x over previous
//
#include <hip/hip_runtime.h>

#define H 32
#define GPB 16  // 32-lane groups per 512-thread block (8 waves)

// tanh(x) = 1 - 2/(1 + exp2(x * 2*log2(e))); saturates correctly at +/-inf.
__device__ __forceinline__ float fast_tanh(float x) {
    float e = __builtin_amdgcn_exp2f(x * 2.8853900817779268f);
    float r = __builtin_amdgcn_rcpf(e + 1.0f);
    return fmaf(-2.0f, r, 1.0f);
}

// acc += (quad-lane q's copy of p) * w — one v_fmac_f32_dpp.
// p regs are only written by ds_read (lgkmcnt-guarded) => no VALU->DPP hazard.
#define QFMA(acc, p, w, q) \
    asm("v_fmac_f32_dpp %0, %1, %2 quad_perm:[" #q "," #q "," #q "," #q "] row_mask:0xf bank_mask:0xf" \
        : "+v"(acc) : "v"(p), "v"(w))

// Column i of the mat-vec: round-robin over the 4 accumulators (8-cycle reuse
// distance >= FMA latency). Per-accumulator order identical to baseline.
#define MV4(i, pv) \
    QFMA(a0, pv, whh[i],      0); \
    QFMA(a1, pv, whh[8 + i],  1); \
    QFMA(a2, pv, whh[16 + i], 2); \
    QFMA(a3, pv, whh[24 + i], 3)

// dpp mov, bound_ctrl=1: shifted-in lanes contribute 0.
#define DPPMOV(x, ctrl) \
    __int_as_float(__builtin_amdgcn_update_dpp(0, __float_as_int(x), (ctrl), 0xf, 0xf, true))
#define ROW_SHR1 0x111
#define ROW_SHR2 0x112
#define ROW_SHR4 0x114

// x-projection: 5 FMAs off broadcast-loaded onehot/reward.
#define XP(oh, rwc) fmaf((oh).x, wih0, fmaf((oh).y, wih1, fmaf((oh).z, wih2, \
                     fmaf((oh).w, wih3, fmaf((rwc), wih4, bias)))))

struct F8 { float4 a, b; };  // gathered 8-chunk (two ds_read_b128 results)

// 512-thread blocks, 1 block/CU -> 8 waves/CU = 2 waves per SIMD (co-issue
// fills the VALU execute slots; proven in R5: 509 -> 348 cyc/wave-step).
// R5's regression was DS-pipe saturation (64 bpermutes/CU/step ~= the whole
// 696-cyc period). Gather via private-LDS write+2x read_b128 = 3 DS ops.
__global__ __launch_bounds__(512, 2) void rnn_fused(
    const float* __restrict__ onehot,   // [B,T,4]
    const float* __restrict__ rewards,  // [B,T]
    const float* __restrict__ W_ih,     // [H,5]
    const float* __restrict__ W_hh,     // [H,H]
    const float* __restrict__ b_ih,     // [H]
    const float* __restrict__ b_hh,     // [H]
    const float* __restrict__ W_ro,     // [4,H]
    const float* __restrict__ b_ro,     // [4]
    float* __restrict__ out_logits,     // [B,T,4]
    float* __restrict__ out_hT,         // [B,H]
    int T)
{
    const int tid = threadIdx.x;
    const int u   = tid & 31;            // hidden unit owned by this lane
    const int wl  = tid & 63;            // lane within the wave64
    const int wv  = tid >> 6;            // wave index within block (0..7)
    const int b   = blockIdx.x * GPB + (tid >> 5);
    const int qp  = u & 3;               // quad position -> which 8-chunk we gather
    const int r   = u >> 3;              // readout row this lane contributes to
    const bool hi = ((u >> 2) & 1) != 0; // which half of our chunk for readout
    const bool writer = (u & 7) == 7;    // lane that stores logit row r

    // Per-wave private 64-float LDS slice: write h, read back 8-chunks.
    // Same-wave DS ops execute in order -> no barrier, no double buffer.
    // Write: stride-1 (2-way, free). Read: 8 distinct 16B lines per wave,
    // 8 lanes broadcast each -> conflict-free.
    __shared__ __align__(16) float hbuf[8 * 64];
    float* wptr = &hbuf[wv * 64 + wl];
    const float4* gp = (const float4*)&hbuf[wv * 64 + (wl & 32) + 8 * qp];

    // ---- persistent per-lane weights ----
    float whh[H];
#pragma unroll
    for (int k = 0; k < 8; ++k) {
        float4 w = *(const float4*)(W_hh + u * H + 4 * k);
        whh[4*k+0] = w.x; whh[4*k+1] = w.y; whh[4*k+2] = w.z; whh[4*k+3] = w.w;
    }
    const float wih0 = W_ih[u*5+0], wih1 = W_ih[u*5+1], wih2 = W_ih[u*5+2],
                wih3 = W_ih[u*5+3], wih4 = W_ih[u*5+4];
    const float bias = b_ih[u] + b_hh[u];
    const float4 wr4 = *(const float4*)(W_ro + r * H + qp * 8 + (hi ? 4 : 0));
    const float bro = b_ro[r];

    const float* oh_ptr = onehot  + (size_t)b * T * 4;
    const float* rw_ptr = rewards + (size_t)b * T;
    float*       lg_ptr = out_logits + (size_t)b * T * 4;

    // ---- two input-register banks (X: oh0..3/rwv, Y: qh0..3/qrw) so the
    //      x-projection can be computed INSIDE each step (gather-latency
    //      filler) without being clobbered by the next prefetch ----
    float4 oh0, oh1, oh2, oh3, rwv;
    float4 qh0, qh1, qh2, qh3, qrw;

    auto loadX = [&](int t) {
        oh0 = *(const float4*)(oh_ptr + (size_t)t * 4);
        oh1 = *(const float4*)(oh_ptr + (size_t)(t + 1) * 4);
        oh2 = *(const float4*)(oh_ptr + (size_t)(t + 2) * 4);
        oh3 = *(const float4*)(oh_ptr + (size_t)(t + 3) * 4);
        rwv = *(const float4*)(rw_ptr + t);
    };
    auto loadY = [&](int t) {
        qh0 = *(const float4*)(oh_ptr + (size_t)t * 4);
        qh1 = *(const float4*)(oh_ptr + (size_t)(t + 1) * 4);
        qh2 = *(const float4*)(oh_ptr + (size_t)(t + 2) * 4);
        qh3 = *(const float4*)(oh_ptr + (size_t)(t + 3) * 4);
        qrw = *(const float4*)(rw_ptr + t);
    };

    float hj = 0.0f;                     // h^{(-1)} = 0
    F8 pA, pB;                           // double-buffered gathered chunk

    // logits_t from a gathered h^{(t)} chunk buffer
    auto readout = [&](const F8& p, int t) {
        float s0 = hi ? p.b.x : p.a.x;
        float s1 = hi ? p.b.y : p.a.y;
        float s2 = hi ? p.b.z : p.a.z;
        float s3 = hi ? p.b.w : p.a.w;
        float s = fmaf(s3, wr4.w, fmaf(s2, wr4.z, fmaf(s1, wr4.y, s0 * wr4.x)));
        s += DPPMOV(s, ROW_SHR1);
        s += DPPMOV(s, ROW_SHR2);
        s += DPPMOV(s, ROW_SHR4);        // lane (8r+7) holds full dot of row r
        if (writer) lg_ptr[(size_t)t * 4 + r] = s + bro;
    };

    // One recurrence step. h^{(t-1)} goes to LDS (1 ds_write_b32) and the
    // lane's 8-chunk comes back as two ds_read_b128 into pN. Readout of
    // h^{(t-2)} plus the x-projection fill the LDS round-trip; then the
    // round-robin mat-vec and tanh.
    auto step = [&](F8& pN, const F8& pO,
                    const float4& oh, float rwc, int t, bool ro) {
        *wptr = hj;                      // ds_write_b32 (in-order DS pipe)
        pN.a = gp[0];                    // ds_read_b128: h[8qp .. 8qp+3]
        pN.b = gp[1];                    // ds_read_b128: h[8qp+4 .. 8qp+7]
        if (ro) readout(pO, t - 2);      // latency filler (depends only on pO)
        const float xp = XP(oh, rwc);    // more filler (prefetched regs only)
        float a0 = xp, a1 = 0.f, a2 = 0.f, a3 = 0.f;
        MV4(0, pN.a.x); MV4(1, pN.a.y); MV4(2, pN.a.z); MV4(3, pN.a.w);
        MV4(4, pN.b.x); MV4(5, pN.b.y); MV4(6, pN.b.z); MV4(7, pN.b.w);
        hj = fast_tanh((a0 + a1) + (a2 + a3));
    };

    // ---- prologue: banks X=(t 0..3), Y=(t 4..7); steps 0..7 peeled ----
    loadX(0);
    loadY(4);
    step(pA, pB, oh0, rwv.x, 0, false);
    step(pB, pA, oh1, rwv.y, 1, false);
    step(pA, pB, oh2, rwv.z, 2, true);
    step(pB, pA, oh3, rwv.w, 3, true);
    loadX(8);                            // refill X for t = 8..11
    step(pA, pB, qh0, qrw.x, 4, true);
    step(pB, pA, qh1, qrw.y, 5, true);
    step(pA, pB, qh2, qrw.z, 6, true);
    step(pB, pA, qh3, qrw.w, 7, true);

    // ---- steady state: 8 steps per iteration, banks ping-pong ----
    for (int tb = 8; tb < T; tb += 8) {
        if (tb + 4 < T) loadY(tb + 4);   // refill Y while X block runs
        step(pA, pB, oh0, rwv.x, tb + 0, true);
        step(pB, pA, oh1, rwv.y, tb + 1, true);
        step(pA, pB, oh2, rwv.z, tb + 2, true);
        step(pB, pA, oh3, rwv.w, tb + 3, true);
        if (tb + 8 < T) loadX(tb + 8);   // refill X while Y block runs
        step(pA, pB, qh0, qrw.x, tb + 4, true);
        step(pB, pA, qh1, qrw.y, tb + 5, true);
        step(pA, pB, qh2, qrw.z, tb + 6, true);
        step(pB, pA, qh3, qrw.w, tb + 7, true);
    }

    // ---- epilogue (last step was t = T-1, wrote pB = gather(h^{T-2})) ----
    readout(pB, T - 2);
    *wptr = hj;                          // hj = h^{(T-1)}
    pA.a = gp[0];
    pA.b = gp[1];
    readout(pA, T - 1);                  // logits_{T-1} from h^{(T-1)}
    out_hT[(size_t)b * H + u] = hj;      // h_T
}

extern "C" void kernel_launch(void* const* d_in, const int* in_sizes, int n_in,
                              void* d_out, int out_size, void* d_ws, size_t ws_size,
                              hipStream_t stream) {
    const float* onehot  = (const float*)d_in[0];
    const float* rewards = (const float*)d_in[1];
    const float* W_ih    = (const float*)d_in[2];
    const float* W_hh    = (const float*)d_in[3];
    const float* b_ih    = (const float*)d_in[4];
    const float* b_hh    = (const float*)d_in[5];
    const float* W_ro    = (const float*)d_in[6];
    const float* b_ro    = (const float*)d_in[7];

    const int T = 1024;                  // per setup_inputs()
    const int B = in_sizes[1] / T;       // in_sizes[1] = B*T

    float* out_logits = (float*)d_out;                        // [B,T,4]
    float* out_hT     = (float*)d_out + (size_t)B * T * 4;    // [B,H]

    dim3 block(512);                     // 8 waves/block, 1 block/CU -> 2 waves/SIMD
    dim3 grid(B / GPB);                  // = 128 blocks
    rnn_fused<<<grid, block, 0, stream>>>(onehot, rewards, W_ih, W_hh,
                                          b_ih, b_hh, W_ro, b_ro,
                                          out_logits, out_hT, T);
}

// Round 7
// 342.853 us; speedup vs baseline: 1.1482x; 1.0733x over previous
//
#include <hip/hip_runtime.h>

#define H 32
#define GPB 8   // 32-lane groups per 256-thread block

// tanh(x) = 1 - 2/(1 + exp2(x * 2*log2(e))); saturates correctly at +/-inf.
__device__ __forceinline__ float fast_tanh(float x) {
    float e = __builtin_amdgcn_exp2f(x * 2.8853900817779268f);
    float r = __builtin_amdgcn_rcpf(e + 1.0f);
    return fmaf(-2.0f, r, 1.0f);
}

// dpp mov via builtin => compiler inserts any required VALU->DPP hazard nops.
// bound_ctrl=1: out-of-row lanes read 0 (only matters for SHR patterns).
#define DPPMOV(x, ctrl) \
    __int_as_float(__builtin_amdgcn_update_dpp(0, __float_as_int(x), (ctrl), 0xf, 0xf, true))
#define QP0 0x00    // quad_perm:[0,0,0,0]
#define QP1 0x55    // quad_perm:[1,1,1,1]
#define QP2 0xAA    // quad_perm:[2,2,2,2]
#define QP3 0xFF    // quad_perm:[3,3,3,3]
#define RR4 0x124   // row_ror:4  (dst[i] = src[(i-4)&15] within 16-lane row)
#define SHR4 0x114  // row_shr:4
#define SHR8 0x118  // row_shr:8
#define SWZ_X16 0x401F  // ds_swizzle BitMode: lane ^ 16 (per 32-lane group)

// x-projection: 5 FMAs off broadcast-loaded onehot/reward.
#define XP(oh, rwc) fmaf((oh).x, wih0, fmaf((oh).y, wih1, fmaf((oh).z, wih2, \
                     fmaf((oh).w, wih3, fmaf((rwc), wih4, bias)))))

// One stage: broadcast quad elements b=0..3 of rr, FMA into the 4 accumulators.
#define STAGE(rr, W, j0) do { \
    q0 = DPPMOV(rr, QP0); q1 = DPPMOV(rr, QP1); \
    q2 = DPPMOV(rr, QP2); q3 = DPPMOV(rr, QP3); \
    a0 = fmaf(q0, W[j0+0], a0); a1 = fmaf(q1, W[j0+1], a1); \
    a2 = fmaf(q2, W[j0+2], a2); a3 = fmaf(q3, W[j0+3], a3); \
} while (0)

// Recurrence chain is latency-bound (wall = T x chain; R4-R6 evidence), and
// DS round trips dominated the chain. This version gathers h via DPP only:
// own 16-half by quad_perm broadcasts + row_ror:4 rotations (weights
// pre-permuted to match), other 16-half via ONE ds_swizzle(xor16) whose
// latency hides under the own-half FMA stream. 1 DS op/step total.
__global__ __launch_bounds__(256, 1) void rnn_fused(
    const float* __restrict__ onehot,   // [B,T,4]
    const float* __restrict__ rewards,  // [B,T]
    const float* __restrict__ W_ih,     // [H,5]
    const float* __restrict__ W_hh,     // [H,H]
    const float* __restrict__ b_ih,     // [H]
    const float* __restrict__ b_hh,     // [H]
    const float* __restrict__ W_ro,     // [4,H]
    const float* __restrict__ b_ro,     // [4]
    float* __restrict__ out_logits,     // [B,T,4]
    float* __restrict__ out_hT,         // [B,H]
    int T)
{
    const int tid = threadIdx.x;
    const int u   = tid & 31;            // hidden unit owned by this lane
    const int b   = blockIdx.x * GPB + (tid >> 5);
    const bool wr = (u >= 12) && (u < 16);  // lanes 12..15 store logits 0..3

    // ---- pre-permuted W_hh so the rotating quad-broadcast sees the right k.
    // At stage s (after s row_ror:4), quad-broadcast b delivers
    //   h[(u&16) + ((4*((u>>2)&3) + b - 4*s) & 15)]   (own half)
    // and the same with base^16 for the swizzled half.
    float wown[16], woth[16];
    {
        const int base = u & 16;
        const int rb   = 4 * ((u >> 2) & 3);
        #pragma unroll
        for (int j = 0; j < 16; ++j) {
            const int s = j >> 2, bq = j & 3;
            const int kin = (rb + bq - 4 * s) & 15;
            wown[j] = W_hh[u * H + base + kin];
            woth[j] = W_hh[u * H + (base ^ 16) + kin];
        }
    }
    const float wih0 = W_ih[u*5+0], wih1 = W_ih[u*5+1], wih2 = W_ih[u*5+2],
                wih3 = W_ih[u*5+3], wih4 = W_ih[u*5+4];
    const float bias = b_ih[u] + b_hh[u];
    // readout: lane u covers row r=u&3, columns = its quad and the twin quad.
    const float4 wroq  = *(const float4*)(W_ro + (u & 3) * H + (u & ~3));
    const float4 wroq2 = *(const float4*)(W_ro + (u & 3) * H + ((u & ~3) ^ 16));
    const float broz = b_ro[u & 3];

    const float* oh_ptr = onehot  + (size_t)b * T * 4;
    const float* rw_ptr = rewards + (size_t)b * T;
    float*       lg_ptr = out_logits + (size_t)b * T * 4;

    // ---- two input-register banks so prefetch never clobbers live operands
    float4 oh0, oh1, oh2, oh3, rwv;
    float4 qh0, qh1, qh2, qh3, qrw;
    auto loadX = [&](int t) {
        oh0 = *(const float4*)(oh_ptr + (size_t)t * 4);
        oh1 = *(const float4*)(oh_ptr + (size_t)(t + 1) * 4);
        oh2 = *(const float4*)(oh_ptr + (size_t)(t + 2) * 4);
        oh3 = *(const float4*)(oh_ptr + (size_t)(t + 3) * 4);
        rwv = *(const float4*)(rw_ptr + t);
    };
    auto loadY = [&](int t) {
        qh0 = *(const float4*)(oh_ptr + (size_t)t * 4);
        qh1 = *(const float4*)(oh_ptr + (size_t)(t + 1) * 4);
        qh2 = *(const float4*)(oh_ptr + (size_t)(t + 2) * 4);
        qh3 = *(const float4*)(oh_ptr + (size_t)(t + 3) * 4);
        qrw = *(const float4*)(rw_ptr + t);
    };

    float hj;  // running hidden state h^{t}

    // One step: consumes hj = h^{t-1}, produces hj = h^{t}; also emits
    // logits_{t-1} (readout reuses the stage-0 broadcasts of h^{t-1}).
    auto step = [&](const float4& oh, float rwc, int emit_t) {
        const float h0 = hj;
        const int hsb = __builtin_amdgcn_ds_swizzle(__float_as_int(h0), SWZ_X16);
        float a0 = XP(oh, rwc), a1 = 0.f, a2 = 0.f, a3 = 0.f;
        float q0, q1, q2, q3;
        // own 16-half (4 stages, rotating by 4 lanes within the 16-row)
        STAGE(h0, wown, 0);
        float pr = q0 * wroq.x;                  // readout row partials
        pr = fmaf(q1, wroq.y, pr);
        pr = fmaf(q2, wroq.z, pr);
        pr = fmaf(q3, wroq.w, pr);
        float r = DPPMOV(h0, RR4);
        STAGE(r, wown, 4);
        r = DPPMOV(r, RR4);
        STAGE(r, wown, 8);
        r = DPPMOV(r, RR4);
        STAGE(r, wown, 12);
        // other 16-half (swizzle latency hidden under the work above)
        const float hs = __int_as_float(hsb);
        STAGE(hs, woth, 0);
        pr = fmaf(q0, wroq2.x, pr);
        pr = fmaf(q1, wroq2.y, pr);
        pr = fmaf(q2, wroq2.z, pr);
        pr = fmaf(q3, wroq2.w, pr);
        r = DPPMOV(hs, RR4);
        STAGE(r, woth, 4);
        r = DPPMOV(r, RR4);
        STAGE(r, woth, 8);
        r = DPPMOV(r, RR4);
        STAGE(r, woth, 12);
        // readout finish: reduce quad-partials down the 16-row; lanes 12..15
        // hold logits 0..3 of this 32-group (16B coalesced store).
        float t1 = pr + DPPMOV(pr, SHR4);
        float t2 = t1 + DPPMOV(t1, SHR8);
        if (wr) lg_ptr[(size_t)emit_t * 4 + (u & 3)] = t2 + broz;
        hj = fast_tanh((a0 + a1) + (a2 + a3));
    };

    // ---- prologue ----
    loadX(0);
    loadY(4);
    hj = fast_tanh(XP(oh0, rwv.x));      // t = 0 (h^{-1} = 0: mat-vec vanishes)
    step(oh1, rwv.y, 0);                 // t = 1, emits logits_0
    step(oh2, rwv.z, 1);
    step(oh3, rwv.w, 2);
    loadX(8);
    step(qh0, qrw.x, 3);                 // t = 4..7
    step(qh1, qrw.y, 4);
    step(qh2, qrw.z, 5);
    step(qh3, qrw.w, 6);
    loadY(12);

    // ---- steady state: 8 steps / iteration ----
    for (int tb = 8; tb < T; tb += 8) {
        step(oh0, rwv.x, tb - 1);
        step(oh1, rwv.y, tb + 0);
        step(oh2, rwv.z, tb + 1);
        step(oh3, rwv.w, tb + 2);
        if (tb + 8 < T) loadX(tb + 8);
        step(qh0, qrw.x, tb + 3);
        step(qh1, qrw.y, tb + 4);
        step(qh2, qrw.z, tb + 5);
        step(qh3, qrw.w, tb + 6);
        if (tb + 12 < T) loadY(tb + 12);
    }

    // ---- tail: logits_{T-1} from h^{T-1} ----
    {
        const int hsb = __builtin_amdgcn_ds_swizzle(__float_as_int(hj), SWZ_X16);
        float q0 = DPPMOV(hj, QP0), q1 = DPPMOV(hj, QP1),
              q2 = DPPMOV(hj, QP2), q3 = DPPMOV(hj, QP3);
        float pr = q0 * wroq.x;
        pr = fmaf(q1, wroq.y, pr);
        pr = fmaf(q2, wroq.z, pr);
        pr = fmaf(q3, wroq.w, pr);
        const float hs = __int_as_float(hsb);
        q0 = DPPMOV(hs, QP0); q1 = DPPMOV(hs, QP1);
        q2 = DPPMOV(hs, QP2); q3 = DPPMOV(hs, QP3);
        pr = fmaf(q0, wroq2.x, pr);
        pr = fmaf(q1, wroq2.y, pr);
        pr = fmaf(q2, wroq2.z, pr);
        pr = fmaf(q3, wroq2.w, pr);
        float t1 = pr + DPPMOV(pr, SHR4);
        float t2 = t1 + DPPMOV(t1, SHR8);
        if (wr) lg_ptr[(size_t)(T - 1) * 4 + (u & 3)] = t2 + broz;
    }
    out_hT[(size_t)b * H + u] = hj;      // h_T
}

extern "C" void kernel_launch(void* const* d_in, const int* in_sizes, int n_in,
                              void* d_out, int out_size, void* d_ws, size_t ws_size,
                              hipStream_t stream) {
    const float* onehot  = (const float*)d_in[0];
    const float* rewards = (const float*)d_in[1];
    const float* W_ih    = (const float*)d_in[2];
    const float* W_hh    = (const float*)d_in[3];
    const float* b_ih    = (const float*)d_in[4];
    const float* b_hh    = (const float*)d_in[5];
    const float* W_ro    = (const float*)d_in[6];
    const float* b_ro    = (const float*)d_in[7];

    const int T = 1024;                  // per setup_inputs()
    const int B = in_sizes[1] / T;       // in_sizes[1] = B*T

    float* out_logits = (float*)d_out;                        // [B,T,4]
    float* out_hT     = (float*)d_out + (size_t)B * T * 4;    // [B,H]

    dim3 block(256);                     // 4 waves/block, 1024 waves total
    dim3 grid(B / GPB);                  // = 256 blocks -> 1 wave/SIMD chip-wide
    rnn_fused<<<grid, block, 0, stream>>>(onehot, rewards, W_ih, W_hh,
                                          b_ih, b_hh, W_ro, b_ro,
                                          out_logits, out_hT, T);
}